// Round 7
// baseline (216.897 us; speedup 1.0000x reference)
//
#include <hip/hip_runtime.h>
#include <stdint.h>

#define M_DIM 8192
#define K_DIM 4096
#define N_DIM 4096

using i32x4 = __attribute__((ext_vector_type(4))) int;

typedef const __attribute__((address_space(1))) void g_void;
typedef __attribute__((address_space(3))) void lds_void;

__device__ __forceinline__ void gload_lds16(const void* g, void* l) {
  // async global->LDS, 16B/lane; LDS dest = wave-uniform base + lane*16
  __builtin_amdgcn_global_load_lds((g_void*)g, (lds_void*)l, 16, 0, 0);
}

__device__ __forceinline__ void barrier_raw() {
  asm volatile("" ::: "memory");
  __builtin_amdgcn_s_barrier();
  asm volatile("" ::: "memory");
}

__device__ __forceinline__ int sign4(float4 v) {
  int a = (v.x > 0.f) - (v.x < 0.f);
  int b = (v.y > 0.f) - (v.y < 0.f);
  int c = (v.z > 0.f) - (v.z < 0.f);
  int d = (v.w > 0.f) - (v.w < 0.f);
  return (a & 255) | ((b & 255) << 8) | ((c & 255) << 16) | ((d & 255) << 24);
}

// ---- pack x: fp32 [M][K] -> int8 sign [M][K] ----
__global__ void pack_x_kernel(const float* __restrict__ in,
                              int8_t* __restrict__ out, long n) {
  long i0 = ((long)blockIdx.x * blockDim.x + threadIdx.x) * 16;
  long stride = (long)gridDim.x * blockDim.x * 16;
  for (long i = i0; i < n; i += stride) {
    const float4* p = reinterpret_cast<const float4*>(in + i);
    i32x4 r;
    r.x = sign4(p[0]);
    r.y = sign4(p[1]);
    r.z = sign4(p[2]);
    r.w = sign4(p[3]);
    *reinterpret_cast<i32x4*>(out + i) = r;
  }
}

// ---- pack w: fp32 [K][N] -> int8 sign, TRANSPOSED to [N][K] ----
__global__ void pack_wt_kernel(const float* __restrict__ w,
                               int8_t* __restrict__ wt) {
  __shared__ int8_t tile[64 * 68];
  int n0 = blockIdx.x * 64;
  int k0 = blockIdx.y * 64;
  int t = threadIdx.x;
#pragma unroll
  for (int i = 0; i < 16; ++i) {
    int flat = t + 256 * i;
    int r = flat >> 6;          // k-local
    int c = flat & 63;          // n-local (coalesced)
    float v = w[(long)(k0 + r) * N_DIM + n0 + c];
    tile[c * 68 + r] = (int8_t)((v > 0.f) - (v < 0.f));
  }
  __syncthreads();
#pragma unroll
  for (int i = 0; i < 4; ++i) {
    int flat = t + 256 * i;
    int nn = flat >> 4;
    int kk = (flat & 15) << 2;
    int word = *reinterpret_cast<const int*>(&tile[nn * 68 + kk]);
    *reinterpret_cast<int*>(wt + (long)(n0 + nn) * K_DIM + k0 + kk) = word;
  }
}

// ---- i8 GEMM: 256x256 tile, BK=64, 8 waves (2Mx4N), mfma_i32_16x16x64_i8.
// A: LDS 4-deep ring (64 KiB, global_load_lds, R2 zero-conflict swizzle).
// B: direct global->VGPR, *** 2-tile *** register prefetch (3 rotating sets).
// vmcnt ledger (in-order; per tile issue {B(t+2)x4, A(t+2)x2}):
//   gate of tile t needs ONLY B(t) + A(t) retired; 12 newer loads (tiles
//   t+1, t+2) stay in flight -> vmcnt(12). R6's vmcnt(6) forced A(t+1)
//   (HBM ~900cyc, 1 tile old) to retire every tile = the exposed stall.
// Slot reuse: A(t+2) -> slot (t+2)&3, last read at t-2, reads retired by
// that tile's lgkmcnt(0), two barriers passed since.
template <int VM, bool ISSUE>
__device__ __forceinline__ void tile_step(
    int t, const int8_t* __restrict__ Asrc, const int8_t* __restrict__ Bsrc,
    long sOff0, long sOff1, long bOffG, int dstOff, int8_t* lds, int aRd,
    i32x4 (&bfC)[4], i32x4 (&bfN)[4], i32x4 (&acc)[8][4]) {
  const int8_t* buf = lds + (t & 3) * 16384;
  // step1: B(t+2) fragment prefetch (global -> VGPR, set (t+2)%3)
  if (ISSUE) {
    long kb = bOffG + (long)(t + 2) * 64;
#pragma unroll
    for (int n = 0; n < 4; ++n)
      bfN[n] =
          *reinterpret_cast<const i32x4*>(Bsrc + kb + (long)n * 16 * K_DIM);
  }
  // step2: A(t+2) staging (global -> LDS)
  if (ISSUE) {
    long kn = (long)(t + 2) * 64;
    int8_t* nbuf = lds + ((t + 2) & 3) * 16384;
    gload_lds16(Asrc + sOff0 + kn, nbuf + dstOff);
    gload_lds16(Asrc + sOff1 + kn, nbuf + 8192 + dstOff);
  }
  // step3: counted vm-gate (retires B(t) + A(t); 12 newer stay in flight)
  if (VM == 12) asm volatile("s_waitcnt vmcnt(12)" ::: "memory");
  else if (VM == 6) asm volatile("s_waitcnt vmcnt(6)" ::: "memory");
  else asm volatile("s_waitcnt vmcnt(0)" ::: "memory");
  // step4: one barrier per tile (A(t) in LDS, visible to all waves)
  barrier_raw();
  // step5: A fragment reads for tile t
  i32x4 af[8];
#pragma unroll
  for (int m = 0; m < 8; ++m)
    af[m] = *reinterpret_cast<const i32x4*>(buf + aRd + m * 1024);
  // ph0
  asm volatile("s_waitcnt lgkmcnt(4)" ::: "memory");  // af[0..3] ready
  __builtin_amdgcn_sched_barrier(0);
  __builtin_amdgcn_s_setprio(1);
#pragma unroll
  for (int m = 0; m < 4; ++m)
#pragma unroll
    for (int n = 0; n < 4; ++n)
      acc[m][n] = __builtin_amdgcn_mfma_i32_16x16x64_i8(af[m], bfC[n],
                                                        acc[m][n], 0, 0, 0);
  __builtin_amdgcn_s_setprio(0);
  // ph1
  asm volatile("s_waitcnt lgkmcnt(0)" ::: "memory");  // af[4..7] ready
  __builtin_amdgcn_sched_barrier(0);
  __builtin_amdgcn_s_setprio(1);
#pragma unroll
  for (int m = 0; m < 4; ++m)
#pragma unroll
    for (int n = 0; n < 4; ++n)
      acc[4 + m][n] = __builtin_amdgcn_mfma_i32_16x16x64_i8(af[4 + m], bfC[n],
                                                            acc[4 + m][n], 0, 0, 0);
  __builtin_amdgcn_s_setprio(0);
}

__global__ __launch_bounds__(512, 2) void gemm_i8_kernel(
    const int8_t* __restrict__ A, const int8_t* __restrict__ B,
    float* __restrict__ C) {
  __shared__ __align__(16) int8_t lds[4 * 16384];  // 64 KiB, A only

  // XCD-aware bijective swizzle: nwg = 512 = 8 * 64
  int bid = blockIdx.x;
  int wg = (bid & 7) * 64 + (bid >> 3);
  int bm = wg >> 4;  // M/256 = 32
  int bn = wg & 15;  // N/256 = 16

  int tid = threadIdx.x;
  int wid = tid >> 6;
  int lane = tid & 63;
  int wr = wid >> 2;  // 0..1 (M)
  int wc = wid & 3;   // 0..3 (N)

  const int8_t* Asrc = A + (long)bm * 256 * K_DIM;
  const int8_t* Bsrc = B + (long)bn * 256 * K_DIM;

  // A staging (R2-proven layout): dst chunk = tid; row = tid>>2, c = tid&3;
  // src chunk = (tid&3) ^ ((row>>1)&3) = (tid&3) ^ ((tid>>3)&3)
  int srcChunk = ((tid & 3) ^ ((tid >> 3) & 3)) << 4;
  long sOff0 = (long)(tid >> 2) * K_DIM + srcChunk;  // rows 0..127
  long sOff1 = sOff0 + 128L * K_DIM;                 // rows 128..255
  int dstOff = wid * 1024;  // wave-uniform; HW adds lane*16

  // A frag reads (R2-proven, 0 conflicts): row = wr*128 + m*16 + (lane&15),
  // chunk = (lane>>4) ^ f(row), f = ((lane&15)>>1)&3
  int rswz = ((lane >> 4) ^ (((lane & 15) >> 1) & 3)) << 4;
  int aRd = (wr * 128 + (lane & 15)) * 64 + rswz;

  // B direct-global frag base: row = wc*64 + n*16 + (lane&15), k-chunk lane>>4
  long bOffG = (long)(wc * 64 + (lane & 15)) * K_DIM + ((lane >> 4) << 4);

  i32x4 bf0[4], bf1[4], bf2[4];
  i32x4 acc[8][4] = {};

  // prologue: B(0)->bf0, A(0); B(1)->bf1, A(1)   (order: B,A,B,A)
#pragma unroll
  for (int n = 0; n < 4; ++n)
    bf0[n] = *reinterpret_cast<const i32x4*>(Bsrc + bOffG + (long)n * 16 * K_DIM);
  gload_lds16(Asrc + sOff0, lds + dstOff);
  gload_lds16(Asrc + sOff1, lds + 8192 + dstOff);
#pragma unroll
  for (int n = 0; n < 4; ++n)
    bf1[n] = *reinterpret_cast<const i32x4*>(Bsrc + bOffG + 64 +
                                             (long)n * 16 * K_DIM);
  gload_lds16(Asrc + sOff0 + 64, lds + 16384 + dstOff);
  gload_lds16(Asrc + sOff1 + 64, lds + 16384 + 8192 + dstOff);
  asm volatile("s_waitcnt vmcnt(6)" ::: "memory");  // B(0)+A(0) landed
  barrier_raw();

  // main: t = 0..59 in 3-step rotation (use t%3, load (t+2)%3)
#pragma unroll 1
  for (int tt = 0; tt < 60; tt += 3) {
    tile_step<12, true>(tt, Asrc, Bsrc, sOff0, sOff1, bOffG, dstOff, lds, aRd,
                        bf0, bf2, acc);
    tile_step<12, true>(tt + 1, Asrc, Bsrc, sOff0, sOff1, bOffG, dstOff, lds,
                        aRd, bf1, bf0, acc);
    tile_step<12, true>(tt + 2, Asrc, Bsrc, sOff0, sOff1, bOffG, dstOff, lds,
                        aRd, bf2, bf1, acc);
  }
  // tail: t=60 (use bf0, load bf2=B62), 61 (bf1, load bf0=B63), 62, 63
  tile_step<12, true>(60, Asrc, Bsrc, sOff0, sOff1, bOffG, dstOff, lds, aRd,
                      bf0, bf2, acc);
  tile_step<12, true>(61, Asrc, Bsrc, sOff0, sOff1, bOffG, dstOff, lds, aRd,
                      bf1, bf0, acc);
  tile_step<6, false>(62, Asrc, Bsrc, sOff0, sOff1, bOffG, dstOff, lds, aRd,
                      bf2, bf1, acc);
  tile_step<0, false>(63, Asrc, Bsrc, sOff0, sOff1, bOffG, dstOff, lds, aRd,
                      bf0, bf2, acc);

  // C/D 16x16 layout: col = lane&15, row = (lane>>4)*4 + reg
  long row0 = (long)bm * 256 + wr * 128 + ((lane >> 4) << 2);
  long col0 = (long)bn * 256 + wc * 64 + (lane & 15);
#pragma unroll
  for (int m = 0; m < 8; ++m)
#pragma unroll
    for (int n = 0; n < 4; ++n)
#pragma unroll
      for (int r = 0; r < 4; ++r)
        C[(row0 + m * 16 + r) * N_DIM + col0 + n * 16] = (float)acc[m][n][r];
}

extern "C" void kernel_launch(void* const* d_in, const int* in_sizes, int n_in,
                              void* d_out, int out_size, void* d_ws, size_t ws_size,
                              hipStream_t stream) {
  const float* x = (const float*)d_in[0];
  const float* w = (const float*)d_in[1];
  float* out = (float*)d_out;

  int8_t* xb = (int8_t*)d_ws;                // 32 MB: sign(x) [M][K]
  int8_t* wbt = xb + (size_t)M_DIM * K_DIM;  // 16 MB: sign(w)^T [N][K]

  pack_x_kernel<<<2048, 256, 0, stream>>>(x, xb, (long)M_DIM * K_DIM);
  pack_wt_kernel<<<dim3(N_DIM / 64, K_DIM / 64), 256, 0, stream>>>(w, wbt);
  gemm_i8_kernel<<<512, 512, 0, stream>>>(xb, wbt, out);
}

// Round 9
// 141.929 us; speedup vs baseline: 1.5282x; 1.5282x over previous
//
#include <hip/hip_runtime.h>
#include <stdint.h>

#define M_DIM 8192
#define K_DIM 4096
#define N_DIM 4096
#define KB2 2048  // packed fp4 bytes per row = K_DIM/2

using i32x4 = __attribute__((ext_vector_type(4))) int;
using i32x8 = __attribute__((ext_vector_type(8))) int;
using f32x16 = __attribute__((ext_vector_type(16))) float;

typedef const __attribute__((address_space(1))) void g_void;
typedef __attribute__((address_space(3))) void lds_void;

__device__ __forceinline__ void gload_lds16(const void* g, void* l) {
  // async global->LDS, 16B/lane; LDS dest = wave-uniform base + lane*16
  __builtin_amdgcn_global_load_lds((g_void*)g, (lds_void*)l, 16, 0, 0);
}

__device__ __forceinline__ void barrier_raw() {
  asm volatile("" ::: "memory");
  __builtin_amdgcn_s_barrier();
  asm volatile("" ::: "memory");
}

// fp4 e2m1 sign code. R8 BUG: used 0x4 (=2.0) for +1 -> C was exactly 4x ref
// (absmax 1026 = 3 * |ref|max 342). e2m1: 0010 = 1.0 -> +1 = 0x2, -1 = 0xA.
__device__ __forceinline__ unsigned code4(float v) {
  return v > 0.f ? 0x2u : (v < 0.f ? 0xAu : 0x0u);
}

// ---- pack x: fp32 [M][K] -> fp4-packed [M][K/2] (8 vals -> 1 dword) ----
__global__ void pack_x4_kernel(const float* __restrict__ in,
                               unsigned* __restrict__ out, long n8) {
  long i0 = (long)blockIdx.x * blockDim.x + threadIdx.x;
  long stride = (long)gridDim.x * blockDim.x;
  for (long i = i0; i < n8; i += stride) {
    const float4* p = reinterpret_cast<const float4*>(in + i * 8);
    float4 x0 = p[0], x1 = p[1];
    unsigned w = code4(x0.x) | (code4(x0.y) << 4) | (code4(x0.z) << 8) |
                 (code4(x0.w) << 12) | (code4(x1.x) << 16) |
                 (code4(x1.y) << 20) | (code4(x1.z) << 24) |
                 (code4(x1.w) << 28);
    out[i] = w;
  }
}

// ---- pack w: fp32 [K][N] -> fp4-packed TRANSPOSED [N][K/2] ----
__global__ void pack_wt4_kernel(const float* __restrict__ w,
                                unsigned* __restrict__ wt4) {
  __shared__ uint8_t tile[64 * 68];  // codes, [n][k]
  int n0 = blockIdx.x * 64;
  int k0 = blockIdx.y * 64;
  int t = threadIdx.x;
#pragma unroll
  for (int i = 0; i < 16; ++i) {
    int flat = t + 256 * i;
    int r = flat >> 6;   // k-local
    int c = flat & 63;   // n-local (coalesced)
    tile[c * 68 + r] = (uint8_t)code4(w[(long)(k0 + r) * N_DIM + n0 + c]);
  }
  __syncthreads();
#pragma unroll
  for (int i = 0; i < 2; ++i) {
    int flat = t + 256 * i;  // 512 dwords out
    int nn = flat >> 3;
    int dk = flat & 7;  // dword index within the 64-k slice
    const uint8_t* src = &tile[nn * 68 + dk * 8];
    unsigned word = 0;
#pragma unroll
    for (int e = 0; e < 8; ++e) word |= ((unsigned)src[e]) << (4 * e);
    wt4[(long)(n0 + nn) * (K_DIM / 8) + (k0 >> 3) + dk] = word;
  }
}

// ---- MX-fp4 GEMM: 256x256 tile, BK=128 (64B/row), 8 waves (2Mx4N),
//      mfma_scale_f32_32x32x64_f8f6f4 (fp4, scales=1.0), 4-deep LDS ring
//      (128 KiB), R5's proven vmcnt(8) ledger, 1 barrier/tile.
// LDS layout (linear both sides, NO swizzle): per operand, sub-tiled
//   [mb 0..7][kchunk 0..3][row 0..31] x 16B  (mb = 32-row block).
// Frag read (mb, k-half h): addr = mb*2048 + h*1024 + lane*16 — exactly
// base+lane*16 (m134 reference pattern, conflict-free).
// R8's 4x-exact error validated this entire structure end-to-end.
__device__ __forceinline__ i32x8 lo8(i32x4 r) {
  return __builtin_shufflevector(r, r, 0, 1, 2, 3, -1, -1, -1, -1);
}

#define SCALE1 0x7f7f7f7f  // E8M0 1.0 in every byte

template <int VM, bool ISSUE>
__device__ __forceinline__ void tile_step(
    int t, const uint8_t* __restrict__ Asrc, const uint8_t* __restrict__ Bsrc,
    long off0, long off1, int dstOff, uint8_t* lds, int aRd, int bRd,
    f32x16 (&acc)[4][2]) {
  const uint8_t* buf = lds + (t & 3) * 32768;
  // stage tile t+3 into slot (t+3)&3 (slot last read at t-1; those reads
  // retired at t-1's lgkmcnt(0), and the t-1 end-barrier separates us)
  if (ISSUE) {
    long kn = (long)(t + 3) * 64;
    uint8_t* nbuf = lds + ((t + 3) & 3) * 32768;
    gload_lds16(Asrc + off0 + kn, nbuf + dstOff);
    gload_lds16(Asrc + off1 + kn, nbuf + 8192 + dstOff);
    gload_lds16(Bsrc + off0 + kn, nbuf + 16384 + dstOff);
    gload_lds16(Bsrc + off1 + kn, nbuf + 24576 + dstOff);
  }
  // all 12 frag reads: h0 first (lgkm(6) retires exactly those)
  i32x4 a0[4], b0[2], a1[4], b1[2];
#pragma unroll
  for (int mi = 0; mi < 4; ++mi)
    a0[mi] = *reinterpret_cast<const i32x4*>(buf + aRd + mi * 2048);
#pragma unroll
  for (int ni = 0; ni < 2; ++ni)
    b0[ni] = *reinterpret_cast<const i32x4*>(buf + bRd + ni * 2048);
#pragma unroll
  for (int mi = 0; mi < 4; ++mi)
    a1[mi] = *reinterpret_cast<const i32x4*>(buf + aRd + mi * 2048 + 1024);
#pragma unroll
  for (int ni = 0; ni < 2; ++ni)
    b1[ni] = *reinterpret_cast<const i32x4*>(buf + bRd + ni * 2048 + 1024);
  asm volatile("s_waitcnt lgkmcnt(6)" ::: "memory");  // h0 ready, h1 in flight
  __builtin_amdgcn_sched_barrier(0);
  __builtin_amdgcn_s_setprio(1);
#pragma unroll
  for (int mi = 0; mi < 4; ++mi)
#pragma unroll
    for (int ni = 0; ni < 2; ++ni)
      acc[mi][ni] = __builtin_amdgcn_mfma_scale_f32_32x32x64_f8f6f4(
          lo8(a0[mi]), lo8(b0[ni]), acc[mi][ni], 4, 4, 0, SCALE1, 0, SCALE1);
  __builtin_amdgcn_s_setprio(0);
  asm volatile("s_waitcnt lgkmcnt(0)" ::: "memory");  // h1 ready
  __builtin_amdgcn_sched_barrier(0);
  __builtin_amdgcn_s_setprio(1);
#pragma unroll
  for (int mi = 0; mi < 4; ++mi)
#pragma unroll
    for (int ni = 0; ni < 2; ++ni)
      acc[mi][ni] = __builtin_amdgcn_mfma_scale_f32_32x32x64_f8f6f4(
          lo8(a1[mi]), lo8(b1[ni]), acc[mi][ni], 4, 4, 0, SCALE1, 0, SCALE1);
  __builtin_amdgcn_s_setprio(0);
  // gate: tile t+1 landed for all waves (vmcnt(8) = tiles t+2,t+3 in flight)
  if (VM >= 0) {
    if (VM == 8) asm volatile("s_waitcnt vmcnt(8)" ::: "memory");
    else if (VM == 4) asm volatile("s_waitcnt vmcnt(4)" ::: "memory");
    else asm volatile("s_waitcnt vmcnt(0)" ::: "memory");
    barrier_raw();
  }
}

__global__ __launch_bounds__(512, 2) void gemm_fp4_kernel(
    const uint8_t* __restrict__ A, const uint8_t* __restrict__ B,
    float* __restrict__ C) {
  __shared__ __align__(16) uint8_t lds[4 * 32768];  // 128 KiB

  // XCD-aware bijective swizzle: nwg = 512 = 8 * 64
  int bid = blockIdx.x;
  int wg = (bid & 7) * 64 + (bid >> 3);
  int bm = wg >> 4;  // M/256 = 32
  int bn = wg & 15;  // N/256 = 16

  int tid = threadIdx.x;
  int wid = tid >> 6;
  int lane = tid & 63;
  int wr = wid >> 2;  // 0..1 (M)
  int wc = wid & 3;   // 0..3 (N)

  const uint8_t* Asrc = A + (long)bm * 256 * KB2;
  const uint8_t* Bsrc = B + (long)bn * 256 * KB2;

  // staging decomp for slot s = j*512 + tid: mb=s>>7, c=(s>>5)&3, row=s&31;
  // j=1 only shifts mb by +4 -> off1 = off0 + 128 rows
  long off0 = (long)((tid >> 7) * 32 + (tid & 31)) * KB2 + (((tid >> 5) & 3) << 4);
  long off1 = off0 + 128L * KB2;
  int dstOff = wid * 1024;  // wave-uniform; HW adds lane*16

  // frag read bases (linear lane*16): A mb = wr*4 + mi, B nb = wc*2 + ni
  int aRd = (wr * 4) * 2048 + lane * 16;
  int bRd = 16384 + (wc * 2) * 2048 + lane * 16;

  f32x16 acc[4][2] = {};

  // prologue: stage tiles 0,1,2 (12 loads in flight)
#pragma unroll
  for (int t = 0; t < 3; ++t) {
    uint8_t* buf = lds + t * 32768;
    long k0 = (long)t * 64;
    gload_lds16(Asrc + off0 + k0, buf + dstOff);
    gload_lds16(Asrc + off1 + k0, buf + 8192 + dstOff);
    gload_lds16(Bsrc + off0 + k0, buf + 16384 + dstOff);
    gload_lds16(Bsrc + off1 + k0, buf + 24576 + dstOff);
  }
  asm volatile("s_waitcnt vmcnt(8)" ::: "memory");  // tile 0 landed
  barrier_raw();

#pragma unroll 1
  for (int t = 0; t < 29; ++t)
    tile_step<8, true>(t, Asrc, Bsrc, off0, off1, dstOff, lds, aRd, bRd, acc);
  tile_step<4, false>(29, Asrc, Bsrc, off0, off1, dstOff, lds, aRd, bRd, acc);
  tile_step<0, false>(30, Asrc, Bsrc, off0, off1, dstOff, lds, aRd, bRd, acc);
  tile_step<-1, false>(31, Asrc, Bsrc, off0, off1, dstOff, lds, aRd, bRd, acc);

  // C/D 32x32 layout (R3/R4-verified): col = lane&31,
  // row = (reg&3) + 8*(reg>>2) + 4*(lane>>5)
  long row0 = (long)bm * 256 + wr * 128 + ((lane >> 5) << 2);
  long col0 = (long)bn * 256 + wc * 64 + (lane & 31);
#pragma unroll
  for (int mi = 0; mi < 4; ++mi)
#pragma unroll
    for (int ni = 0; ni < 2; ++ni)
#pragma unroll
      for (int r = 0; r < 16; ++r) {
        long row = row0 + mi * 32 + (r & 3) + ((r >> 2) << 3);
        C[row * N_DIM + col0 + ni * 32] = acc[mi][ni][r];
      }
}

extern "C" void kernel_launch(void* const* d_in, const int* in_sizes, int n_in,
                              void* d_out, int out_size, void* d_ws, size_t ws_size,
                              hipStream_t stream) {
  const float* x = (const float*)d_in[0];
  const float* w = (const float*)d_in[1];
  float* out = (float*)d_out;

  uint8_t* x4 = (uint8_t*)d_ws;                     // 16 MB: fp4 sign(x) [M][K/2]
  uint8_t* w4t = x4 + (size_t)M_DIM * KB2;          // 8 MB: fp4 sign(w)^T [N][K/2]

  pack_x4_kernel<<<2048, 256, 0, stream>>>(x, (unsigned*)x4,
                                           (long)M_DIM * K_DIM / 8);
  pack_wt4_kernel<<<dim3(N_DIM / 64, K_DIM / 64), 256, 0, stream>>>(
      w, (unsigned*)w4t);
  gemm_fp4_kernel<<<512, 512, 0, stream>>>(x4, w4t, out);
}

// Round 10
// 140.221 us; speedup vs baseline: 1.5468x; 1.0122x over previous
//
#include <hip/hip_runtime.h>
#include <stdint.h>

#define M_DIM 8192
#define K_DIM 4096
#define N_DIM 4096
#define KB2 2048  // packed fp4 bytes per row = K_DIM/2

using i32x4 = __attribute__((ext_vector_type(4))) int;
using i32x8 = __attribute__((ext_vector_type(8))) int;
using f32x16 = __attribute__((ext_vector_type(16))) float;

typedef const __attribute__((address_space(1))) void g_void;
typedef __attribute__((address_space(3))) void lds_void;

__device__ __forceinline__ void gload_lds16(const void* g, void* l) {
  // async global->LDS, 16B/lane; LDS dest = wave-uniform base + lane*16
  __builtin_amdgcn_global_load_lds((g_void*)g, (lds_void*)l, 16, 0, 0);
}

__device__ __forceinline__ void barrier_raw() {
  asm volatile("" ::: "memory");
  __builtin_amdgcn_s_barrier();
  asm volatile("" ::: "memory");
}

// fp4 e2m1: 0010 = 1.0 -> +1 = 0x2, -1 = 0xA (R8 used 0x4=2.0 -> 4x ref)
__device__ __forceinline__ unsigned code4(float v) {
  return v > 0.f ? 0x2u : (v < 0.f ? 0xAu : 0x0u);
}

// ---- pack x: fp32 [M][K] -> fp4-packed [M][K/2] (8 vals -> 1 dword) ----
__global__ void pack_x4_kernel(const float* __restrict__ in,
                               unsigned* __restrict__ out, long n8) {
  long i0 = (long)blockIdx.x * blockDim.x + threadIdx.x;
  long stride = (long)gridDim.x * blockDim.x;
  for (long i = i0; i < n8; i += stride) {
    const float4* p = reinterpret_cast<const float4*>(in + i * 8);
    float4 x0 = p[0], x1 = p[1];
    unsigned w = code4(x0.x) | (code4(x0.y) << 4) | (code4(x0.z) << 8) |
                 (code4(x0.w) << 12) | (code4(x1.x) << 16) |
                 (code4(x1.y) << 20) | (code4(x1.z) << 24) |
                 (code4(x1.w) << 28);
    out[i] = w;
  }
}

// ---- pack w: fp32 [K][N] -> fp4-packed TRANSPOSED [N][K/2] ----
__global__ void pack_wt4_kernel(const float* __restrict__ w,
                                unsigned* __restrict__ wt4) {
  __shared__ uint8_t tile[64 * 68];  // codes, [n][k]
  int n0 = blockIdx.x * 64;
  int k0 = blockIdx.y * 64;
  int t = threadIdx.x;
#pragma unroll
  for (int i = 0; i < 16; ++i) {
    int flat = t + 256 * i;
    int r = flat >> 6;   // k-local
    int c = flat & 63;   // n-local (coalesced)
    tile[c * 68 + r] = (uint8_t)code4(w[(long)(k0 + r) * N_DIM + n0 + c]);
  }
  __syncthreads();
#pragma unroll
  for (int i = 0; i < 2; ++i) {
    int flat = t + 256 * i;  // 512 dwords out
    int nn = flat >> 3;
    int dk = flat & 7;  // dword index within the 64-k slice
    const uint8_t* src = &tile[nn * 68 + dk * 8];
    unsigned word = 0;
#pragma unroll
    for (int e = 0; e < 8; ++e) word |= ((unsigned)src[e]) << (4 * e);
    wt4[(long)(n0 + nn) * (K_DIM / 8) + (k0 >> 3) + dk] = word;
  }
}

// ---- MX-fp4 GEMM, R9 structure + cross-barrier read pipelining ----
// Per tile t (steady state):
//  a) lgkm(6)  -> MFMA h0(t)            [t's h1 reads drain underneath]
//  b) vmcnt(4) + barrier                [t+1 staging landed, all waves]
//  c) stage t+3 (slot (t+3)&3) + issue ALL 12 reads of t+1 (h0 first)
//  d) lgkm(12) -> MFMA h1(t)            [t+1's reads drain underneath]
// In-order DS retirement makes the counted lgkm ledger exact.
// WAR audit: staging t+3 -> slot (t-1)&3; at b's barrier every wave
// executed its step-a lgkm(6), which (in-order) retired ALL t-1 reads.
__device__ __forceinline__ i32x8 lo8(i32x4 r) {
  return __builtin_shufflevector(r, r, 0, 1, 2, 3, -1, -1, -1, -1);
}

#define SCALE1 0x7f7f7f7f  // E8M0 1.0 in every byte

template <int VM, bool ISSUE, bool READ>
__device__ __forceinline__ void tile_step(
    int t, const uint8_t* __restrict__ Asrc, const uint8_t* __restrict__ Bsrc,
    long off0, long off1, int dstOff, uint8_t* lds, int aRd, int bRd,
    i32x4 (&aC)[8], i32x4 (&bC)[4], i32x4 (&aN)[8], i32x4 (&bN)[4],
    f32x16 (&acc)[4][2]) {
  // ---- a: MFMA h0(t) ----
  asm volatile("s_waitcnt lgkmcnt(6)" ::: "memory");  // t.h0 ready
  __builtin_amdgcn_sched_barrier(0);
  __builtin_amdgcn_s_setprio(1);
#pragma unroll
  for (int mi = 0; mi < 4; ++mi)
#pragma unroll
    for (int ni = 0; ni < 2; ++ni)
      acc[mi][ni] = __builtin_amdgcn_mfma_scale_f32_32x32x64_f8f6f4(
          lo8(aC[mi]), lo8(bC[ni]), acc[mi][ni], 4, 4, 0, SCALE1, 0, SCALE1);
  __builtin_amdgcn_s_setprio(0);
  // ---- b: vm-gate + single barrier per tile ----
  if (VM >= 0) {
    if (VM == 8) asm volatile("s_waitcnt vmcnt(8)" ::: "memory");
    else if (VM == 4) asm volatile("s_waitcnt vmcnt(4)" ::: "memory");
    else asm volatile("s_waitcnt vmcnt(0)" ::: "memory");
    barrier_raw();
  }
  // ---- c: stage t+3 + read t+1 frags ----
  if (ISSUE) {
    long kn = (long)(t + 3) * 64;
    uint8_t* nbuf = lds + ((t + 3) & 3) * 32768;
    gload_lds16(Asrc + off0 + kn, nbuf + dstOff);
    gload_lds16(Asrc + off1 + kn, nbuf + 8192 + dstOff);
    gload_lds16(Bsrc + off0 + kn, nbuf + 16384 + dstOff);
    gload_lds16(Bsrc + off1 + kn, nbuf + 24576 + dstOff);
  }
  if (READ) {
    const uint8_t* nb = lds + ((t + 1) & 3) * 32768;
#pragma unroll
    for (int mi = 0; mi < 4; ++mi)
      aN[mi] = *reinterpret_cast<const i32x4*>(nb + aRd + mi * 2048);
#pragma unroll
    for (int ni = 0; ni < 2; ++ni)
      bN[ni] = *reinterpret_cast<const i32x4*>(nb + bRd + ni * 2048);
#pragma unroll
    for (int mi = 0; mi < 4; ++mi)
      aN[4 + mi] = *reinterpret_cast<const i32x4*>(nb + aRd + mi * 2048 + 1024);
#pragma unroll
    for (int ni = 0; ni < 2; ++ni)
      bN[2 + ni] = *reinterpret_cast<const i32x4*>(nb + bRd + ni * 2048 + 1024);
  }
  // ---- d: MFMA h1(t) ----
  if (READ)
    asm volatile("s_waitcnt lgkmcnt(12)" ::: "memory");  // t.h1 ready, t+1 in flight
  else
    asm volatile("s_waitcnt lgkmcnt(0)" ::: "memory");
  __builtin_amdgcn_sched_barrier(0);
  __builtin_amdgcn_s_setprio(1);
#pragma unroll
  for (int mi = 0; mi < 4; ++mi)
#pragma unroll
    for (int ni = 0; ni < 2; ++ni)
      acc[mi][ni] = __builtin_amdgcn_mfma_scale_f32_32x32x64_f8f6f4(
          lo8(aC[4 + mi]), lo8(bC[2 + ni]), acc[mi][ni], 4, 4, 0, SCALE1, 0,
          SCALE1);
  __builtin_amdgcn_s_setprio(0);
}

__global__ __launch_bounds__(512, 2) void gemm_fp4_kernel(
    const uint8_t* __restrict__ A, const uint8_t* __restrict__ B,
    float* __restrict__ C) {
  __shared__ __align__(16) uint8_t lds[4 * 32768];  // 128 KiB

  // XCD-aware bijective swizzle: nwg = 512 = 8 * 64
  int bid = blockIdx.x;
  int wg = (bid & 7) * 64 + (bid >> 3);
  int bm = wg >> 4;  // M/256 = 32
  int bn = wg & 15;  // N/256 = 16

  int tid = threadIdx.x;
  int wid = tid >> 6;
  int lane = tid & 63;
  int wr = wid >> 2;  // 0..1 (M)
  int wc = wid & 3;   // 0..3 (N)

  const uint8_t* Asrc = A + (long)bm * 256 * KB2;
  const uint8_t* Bsrc = B + (long)bn * 256 * KB2;

  // staging decomp for slot s = j*512 + tid: mb=s>>7, c=(s>>5)&3, row=s&31
  long off0 = (long)((tid >> 7) * 32 + (tid & 31)) * KB2 + (((tid >> 5) & 3) << 4);
  long off1 = off0 + 128L * KB2;
  int dstOff = wid * 1024;  // wave-uniform; HW adds lane*16

  // frag read bases (linear lane*16): A mb = wr*4 + mi, B nb = wc*2 + ni
  int aRd = (wr * 4) * 2048 + lane * 16;
  int bRd = 16384 + (wc * 2) * 2048 + lane * 16;

  i32x4 aA[8], bA[4], aB[8], bB[4];
  f32x16 acc[4][2] = {};

  // prologue: stage tiles 0,1,2 (12 loads in flight)
#pragma unroll
  for (int t = 0; t < 3; ++t) {
    uint8_t* buf = lds + t * 32768;
    long k0 = (long)t * 64;
    gload_lds16(Asrc + off0 + k0, buf + dstOff);
    gload_lds16(Asrc + off1 + k0, buf + 8192 + dstOff);
    gload_lds16(Bsrc + off0 + k0, buf + 16384 + dstOff);
    gload_lds16(Bsrc + off1 + k0, buf + 24576 + dstOff);
  }
  asm volatile("s_waitcnt vmcnt(8)" ::: "memory");  // tile 0 landed
  barrier_raw();
  // issue tile-0 frag reads (h0 first; retired by t=0's counted lgkm)
#pragma unroll
  for (int mi = 0; mi < 4; ++mi)
    aA[mi] = *reinterpret_cast<const i32x4*>(lds + aRd + mi * 2048);
#pragma unroll
  for (int ni = 0; ni < 2; ++ni)
    bA[ni] = *reinterpret_cast<const i32x4*>(lds + bRd + ni * 2048);
#pragma unroll
  for (int mi = 0; mi < 4; ++mi)
    aA[4 + mi] = *reinterpret_cast<const i32x4*>(lds + aRd + mi * 2048 + 1024);
#pragma unroll
  for (int ni = 0; ni < 2; ++ni)
    bA[2 + ni] = *reinterpret_cast<const i32x4*>(lds + bRd + ni * 2048 + 1024);

#pragma unroll 1
  for (int t = 0; t < 28; t += 2) {
    tile_step<4, true, true>(t, Asrc, Bsrc, off0, off1, dstOff, lds, aRd, bRd,
                             aA, bA, aB, bB, acc);
    tile_step<4, true, true>(t + 1, Asrc, Bsrc, off0, off1, dstOff, lds, aRd,
                             bRd, aB, bB, aA, bA, acc);
  }
  tile_step<4, true, true>(28, Asrc, Bsrc, off0, off1, dstOff, lds, aRd, bRd,
                           aA, bA, aB, bB, acc);  // stages 31
  tile_step<4, false, true>(29, Asrc, Bsrc, off0, off1, dstOff, lds, aRd, bRd,
                            aB, bB, aA, bA, acc);
  tile_step<0, false, true>(30, Asrc, Bsrc, off0, off1, dstOff, lds, aRd, bRd,
                            aA, bA, aB, bB, acc);
  tile_step<-1, false, false>(31, Asrc, Bsrc, off0, off1, dstOff, lds, aRd,
                              bRd, aB, bB, aA, bA, acc);

  // C/D 32x32 layout: col = lane&31, row = (reg&3) + 8*(reg>>2) + 4*(lane>>5)
  long row0 = (long)bm * 256 + wr * 128 + ((lane >> 5) << 2);
  long col0 = (long)bn * 256 + wc * 64 + (lane & 31);
#pragma unroll
  for (int mi = 0; mi < 4; ++mi)
#pragma unroll
    for (int ni = 0; ni < 2; ++ni)
#pragma unroll
      for (int r = 0; r < 16; ++r) {
        long row = row0 + mi * 32 + (r & 3) + ((r >> 2) << 3);
        C[row * N_DIM + col0 + ni * 32] = acc[mi][ni][r];
      }
}

extern "C" void kernel_launch(void* const* d_in, const int* in_sizes, int n_in,
                              void* d_out, int out_size, void* d_ws, size_t ws_size,
                              hipStream_t stream) {
  const float* x = (const float*)d_in[0];
  const float* w = (const float*)d_in[1];
  float* out = (float*)d_out;

  uint8_t* x4 = (uint8_t*)d_ws;                     // 16 MB: fp4 sign(x) [M][K/2]
  uint8_t* w4t = x4 + (size_t)M_DIM * KB2;          // 8 MB: fp4 sign(w)^T [N][K/2]

  pack_x4_kernel<<<2048, 256, 0, stream>>>(x, (unsigned*)x4,
                                           (long)M_DIM * K_DIM / 8);
  pack_wt4_kernel<<<dim3(N_DIM / 64, K_DIM / 64), 256, 0, stream>>>(
      w, (unsigned*)w4t);
  gemm_fp4_kernel<<<512, 512, 0, stream>>>(x4, w4t, out);
}